// Round 3
// baseline (2172.122 us; speedup 1.0000x reference)
//
#include <hip/hip_runtime.h>

#define NN 200000   // nodes
#define NE 600000   // edges
#define NG 8192     // graphs
#define FIN 9
#define HD 128
#define CO 2

// ---------------- degree / norm ----------------
static __global__ void k_init_deg(float* deg) {
    int i = blockIdx.x * 256 + threadIdx.x;
    if (i < NN) deg[i] = 1.0f;              // self-loop weight
}

static __global__ void k_deg_accum(const int* __restrict__ ei, const float* __restrict__ ew,
                                   float* deg) {
    int e = blockIdx.x * 256 + threadIdx.x;
    if (e < NE) atomicAdd(&deg[ei[NE + e]], ew[e]);
}

static __global__ void k_dinv(float* deg) {
    int i = blockIdx.x * 256 + threadIdx.x;
    if (i < NN) {
        float d = deg[i];
        deg[i] = d > 0.0f ? rsqrtf(d) : 0.0f;
    }
}

// ---------------- layer 0 GEMM: x[N,9] @ W0[9,128] ----------------
static __global__ void k_gemm0(const float* __restrict__ x, const float* __restrict__ W0,
                               float* __restrict__ t) {
    int idx = blockIdx.x * 256 + threadIdx.x;
    if (idx >= NN * HD) return;
    int n = idx >> 7, j = idx & 127;
    float acc = 0.f;
#pragma unroll
    for (int k = 0; k < FIN; ++k) acc += x[n * FIN + k] * W0[k * HD + j];
    t[idx] = acc;
}

// ---------------- edge scatter: out[dst] += norm * t[src] ----------------
static __global__ void k_scatter(const int* __restrict__ ei, const float* __restrict__ ew,
                                 const float* __restrict__ dinv, const float* __restrict__ t,
                                 float* __restrict__ out) {
    int tid = blockIdx.x * 256 + threadIdx.x;
    int e = tid >> 6;
    if (e >= NE) return;
    int lane = (tid & 63) * 2;
    int src = ei[e], dst = ei[NE + e];
    float norm = dinv[src] * ew[e] * dinv[dst];
    float2 v = *reinterpret_cast<const float2*>(t + (size_t)src * HD + lane);
    atomicAdd(out + (size_t)dst * HD + lane, norm * v.x);
    atomicAdd(out + (size_t)dst * HD + lane + 1, norm * v.y);
}

// ---------------- self-loop + bias + relu: out = relu(out + dinv^2 * t + b) ----------------
static __global__ void k_slbr(const float* __restrict__ t, const float* __restrict__ dinv,
                              const float* __restrict__ b, float* __restrict__ out) {
    int idx = blockIdx.x * 256 + threadIdx.x;
    if (idx >= NN * HD) return;
    int n = idx >> 7, j = idx & 127;
    float d = dinv[n];
    float v = out[idx] + d * d * t[idx] + b[j];
    out[idx] = v > 0.f ? v : 0.f;
}

// ---------------- GEMM: A[N,128] @ W[128,128], 64x64 tile ----------------
__launch_bounds__(256, 2)
static __global__ void k_gemm128(const float* __restrict__ A, const float* __restrict__ W,
                                 float* __restrict__ out) {
    __shared__ float As[64][128];   // 32 KB
    __shared__ float Ws[128][64];   // 32 KB
    int nb = blockIdx.x >> 1;
    int jb = (blockIdx.x & 1) * 64;
    int n0 = nb * 64;
    int t = threadIdx.x;
    // load A tile (coalesced float4 per row)
    for (int i = t; i < 64 * 32; i += 256) {
        int n = i >> 5, k4 = i & 31;
        reinterpret_cast<float4*>(&As[n][0])[k4] =
            reinterpret_cast<const float4*>(A + (size_t)(n0 + n) * HD)[k4];
    }
    // load W tile
    for (int i = t; i < 128 * 16; i += 256) {
        int k = i >> 4, j4 = i & 15;
        reinterpret_cast<float4*>(&Ws[k][0])[j4] =
            reinterpret_cast<const float4*>(W + (size_t)k * HD + jb)[j4];
    }
    __syncthreads();
    int tn = (t >> 4) * 4;   // 16 node-groups * 4
    int tj = (t & 15) * 4;   // 16 col-groups * 4
    float acc[4][4] = {};
#pragma unroll 4
    for (int k = 0; k < 128; ++k) {
        float a0 = As[tn + 0][k], a1 = As[tn + 1][k], a2 = As[tn + 2][k], a3 = As[tn + 3][k];
        float4 b = *reinterpret_cast<const float4*>(&Ws[k][tj]);
        acc[0][0] += a0 * b.x; acc[0][1] += a0 * b.y; acc[0][2] += a0 * b.z; acc[0][3] += a0 * b.w;
        acc[1][0] += a1 * b.x; acc[1][1] += a1 * b.y; acc[1][2] += a1 * b.z; acc[1][3] += a1 * b.w;
        acc[2][0] += a2 * b.x; acc[2][1] += a2 * b.y; acc[2][2] += a2 * b.z; acc[2][3] += a2 * b.w;
        acc[3][0] += a3 * b.x; acc[3][1] += a3 * b.y; acc[3][2] += a3 * b.z; acc[3][3] += a3 * b.w;
    }
    for (int i = 0; i < 4; ++i) {
        float4 v = make_float4(acc[i][0], acc[i][1], acc[i][2], acc[i][3]);
        *reinterpret_cast<float4*>(out + (size_t)(n0 + tn + i) * HD + jb + tj) = v;
    }
}

// ---------------- pooling ----------------
static __global__ void k_ranges(const int* __restrict__ batch, int* __restrict__ start) {
    int g = blockIdx.x * 256 + threadIdx.x;
    if (g > NG) return;
    int lo = 0, hi = NN;
    while (lo < hi) {
        int mid = (lo + hi) >> 1;
        if (batch[mid] < g) lo = mid + 1; else hi = mid;
    }
    start[g] = lo;
}

static __global__ void k_pool(const float* __restrict__ h, const int* __restrict__ start,
                              float* __restrict__ gx) {
    int g = blockIdx.x;
    int j = threadIdx.x;   // 128
    int s = start[g], e = start[g + 1];
    float acc = 0.f;
    for (int n = s; n < e; ++n) acc += h[(size_t)n * HD + j];
    float cnt = (float)(e - s);
    gx[(size_t)g * HD + j] = acc / fmaxf(cnt, 1.0f);
}

// ---------------- FFN ----------------
static __global__ void k_ffn1(const float* __restrict__ gx, const float* __restrict__ Wf1,
                              const float* __restrict__ bf1, float* __restrict__ z) {
    int idx = blockIdx.x * 256 + threadIdx.x;
    if (idx >= NG * HD) return;
    int g = idx >> 7, j = idx & 127;
    float acc = bf1[j];
#pragma unroll 8
    for (int k = 0; k < HD; ++k) acc += gx[(size_t)g * HD + k] * Wf1[k * HD + j];
    z[idx] = fmaxf(acc, 0.f);
}

static __global__ void k_ffn2(const float* __restrict__ z, const float* __restrict__ Wf2,
                              const float* __restrict__ bf2, float* __restrict__ out) {
    int idx = blockIdx.x * 256 + threadIdx.x;
    if (idx >= NG * CO) return;
    int g = idx >> 1, c = idx & 1;
    float acc = bf2[c];
#pragma unroll 8
    for (int k = 0; k < HD; ++k) acc += z[(size_t)g * HD + k] * Wf2[k * CO + c];
    out[idx] = acc;
}

extern "C" void kernel_launch(void* const* d_in, const int* in_sizes, int n_in,
                              void* d_out, int out_size, void* d_ws, size_t ws_size,
                              hipStream_t stream) {
    const float* x     = (const float*)d_in[0];
    const int*   ei    = (const int*)d_in[1];
    const float* ew    = (const float*)d_in[2];
    const int*   batch = (const int*)d_in[3];
    const float* W0  = (const float*)d_in[4];
    const float* b0  = (const float*)d_in[5];
    const float* W1  = (const float*)d_in[6];
    const float* b1  = (const float*)d_in[7];
    const float* W2  = (const float*)d_in[8];
    const float* b2  = (const float*)d_in[9];
    const float* Wf1 = (const float*)d_in[10];
    const float* bf1 = (const float*)d_in[11];
    const float* Wf2 = (const float*)d_in[12];
    const float* bf2 = (const float*)d_in[13];
    float* out = (float*)d_out;

    char* ws = (char*)d_ws;
    float* bufA = (float*)ws;  ws += (size_t)NN * HD * 4;
    float* bufB = (float*)ws;  ws += (size_t)NN * HD * 4;
    float* dinv = (float*)ws;  ws += (size_t)NN * 4;
    int*   start = (int*)ws;   ws += (size_t)(NG + 1) * 4;
    float* gx   = (float*)ws;  ws += (size_t)NG * HD * 4;
    float* z    = (float*)ws;  ws += (size_t)NG * HD * 4;
    if ((size_t)(ws - (char*)d_ws) > ws_size) return;  // workspace too small

    const int eb = (NN * HD + 255) / 256;       // elementwise over N*H
    const int scb = NE * 64 / 256;              // 64 threads per edge

    // normalization coefficients
    k_init_deg<<<(NN + 255) / 256, 256, 0, stream>>>(dinv);
    k_deg_accum<<<(NE + 255) / 256, 256, 0, stream>>>(ei, ew, dinv);
    k_dinv<<<(NN + 255) / 256, 256, 0, stream>>>(dinv);

    // ---- layer 0 ----
    k_gemm0<<<eb, 256, 0, stream>>>(x, W0, bufA);
    hipMemsetAsync(bufB, 0, (size_t)NN * HD * 4, stream);
    k_scatter<<<scb, 256, 0, stream>>>(ei, ew, dinv, bufA, bufB);
    k_slbr<<<eb, 256, 0, stream>>>(bufA, dinv, b0, bufB);

    // ---- layer 1 ----
    k_gemm128<<<(NN / 64) * 2, 256, 0, stream>>>(bufB, W1, bufA);
    hipMemsetAsync(bufB, 0, (size_t)NN * HD * 4, stream);
    k_scatter<<<scb, 256, 0, stream>>>(ei, ew, dinv, bufA, bufB);
    k_slbr<<<eb, 256, 0, stream>>>(bufA, dinv, b1, bufB);

    // ---- layer 2 ----
    k_gemm128<<<(NN / 64) * 2, 256, 0, stream>>>(bufB, W2, bufA);
    hipMemsetAsync(bufB, 0, (size_t)NN * HD * 4, stream);
    k_scatter<<<scb, 256, 0, stream>>>(ei, ew, dinv, bufA, bufB);
    k_slbr<<<eb, 256, 0, stream>>>(bufA, dinv, b2, bufB);

    // ---- pooling + FFN ----
    k_ranges<<<(NG + 1 + 255) / 256, 256, 0, stream>>>(batch, start);
    k_pool<<<NG, 128, 0, stream>>>(bufB, start, gx);
    k_ffn1<<<(NG * HD + 255) / 256, 256, 0, stream>>>(gx, Wf1, bf1, z);
    k_ffn2<<<(NG * CO + 255) / 256, 256, 0, stream>>>(z, Wf2, bf2, out);
}

// Round 13
// 757.192 us; speedup vs baseline: 2.8687x; 2.8687x over previous
//
#include <hip/hip_runtime.h>

#define NN 200000   // nodes
#define NE 600000   // edges
#define NG 8192     // graphs
#define FIN 9
#define HD 128
#define CO 2
#define NBLK_SCAN ((NN + 1023) / 1024)   // 196

// ---------------- degree + edge-count ----------------
static __global__ void k_init_deg(float* deg) {
    int i = blockIdx.x * 256 + threadIdx.x;
    if (i < NN) deg[i] = 1.0f;              // self-loop weight
}

static __global__ void k_deg_cnt(const int* __restrict__ ei, const float* __restrict__ ew,
                                 float* deg, int* cnt) {
    int e = blockIdx.x * 256 + threadIdx.x;
    if (e < NE) {
        int dst = ei[NE + e];
        atomicAdd(&deg[dst], ew[e]);
        atomicAdd(&cnt[dst], 1);
    }
}

static __global__ void k_dinv(float* deg) {
    int i = blockIdx.x * 256 + threadIdx.x;
    if (i < NN) {
        float d = deg[i];
        deg[i] = d > 0.0f ? rsqrtf(d) : 0.0f;
    }
}

// ---------------- prefix scan (counts -> row_ptr) ----------------
static __global__ void k_scan1(const int* __restrict__ cnt, int* __restrict__ row_ptr,
                               int* __restrict__ bsum) {
    __shared__ int lds[256];
    int b = blockIdx.x, t = threadIdx.x;
    int base = b * 1024 + t * 4;
    int c[4];
    int s = 0;
#pragma unroll
    for (int u = 0; u < 4; ++u) {
        int i = base + u;
        c[u] = (i < NN) ? cnt[i] : 0;
        s += c[u];
    }
    lds[t] = s;
    __syncthreads();
    for (int off = 1; off < 256; off <<= 1) {
        int v = (t >= off) ? lds[t - off] : 0;
        __syncthreads();
        lds[t] += v;
        __syncthreads();
    }
    int run = lds[t] - s;   // exclusive offset within block
#pragma unroll
    for (int u = 0; u < 4; ++u) {
        run += c[u];
        int i = base + u;
        if (i < NN) row_ptr[1 + i] = run;
    }
    if (t == 255) bsum[b] = lds[255];
}

static __global__ void k_scan2(int* bsum) {
    __shared__ int lds[256];
    int t = threadIdx.x;
    lds[t] = (t < NBLK_SCAN) ? bsum[t] : 0;
    __syncthreads();
    for (int off = 1; off < 256; off <<= 1) {
        int v = (t >= off) ? lds[t - off] : 0;
        __syncthreads();
        lds[t] += v;
        __syncthreads();
    }
    if (t < NBLK_SCAN) bsum[t] = lds[t];
}

static __global__ void k_scan3(const int* __restrict__ bsum, int* __restrict__ row_ptr) {
    int i = blockIdx.x * 256 + threadIdx.x;
    if (i == 0) row_ptr[0] = 0;
    if (i < NN) {
        int b = i >> 10;
        int off = b ? bsum[b - 1] : 0;
        row_ptr[1 + i] += off;
    }
}

// fill CSR: per-edge slot grab (cursor = reused cnt buffer, re-zeroed)
static __global__ void k_fill(const int* __restrict__ ei, const float* __restrict__ ew,
                              const float* __restrict__ dinv, const int* __restrict__ row_ptr,
                              int* cursor, int* __restrict__ csr_src, float* __restrict__ csr_w) {
    int e = blockIdx.x * 256 + threadIdx.x;
    if (e >= NE) return;
    int src = ei[e], dst = ei[NE + e];
    int pos = row_ptr[dst] + atomicAdd(&cursor[dst], 1);
    csr_src[pos] = src;
    csr_w[pos] = dinv[src] * ew[e] * dinv[dst];
}

// ---------------- layer 0: propagate raw 9-dim x, then fused GEMM ----------------
static __global__ void k_prop9(const float* __restrict__ x, const float* __restrict__ dinv,
                               const int* __restrict__ row_ptr, const int* __restrict__ csr_src,
                               const float* __restrict__ csr_w, float* __restrict__ xs) {
    int n = blockIdx.x * 256 + threadIdx.x;
    if (n >= NN) return;
    float acc[FIN] = {};
    int s = row_ptr[n], e = row_ptr[n + 1];
    for (int i = s; i < e; ++i) {
        int src = csr_src[i];
        float w = csr_w[i];
#pragma unroll
        for (int k = 0; k < FIN; ++k) acc[k] += w * x[src * FIN + k];
    }
    float d = dinv[n], d2 = d * d;
#pragma unroll
    for (int k = 0; k < FIN; ++k) xs[n * FIN + k] = acc[k] + d2 * x[n * FIN + k];
}

static __global__ void k_gemm0f(const float* __restrict__ xs, const float* __restrict__ W0,
                                const float* __restrict__ b0, float* __restrict__ h) {
    int idx = blockIdx.x * 256 + threadIdx.x;
    if (idx >= NN * HD) return;
    int n = idx >> 7, j = idx & 127;
    float acc = b0[j];
#pragma unroll
    for (int k = 0; k < FIN; ++k) acc += xs[n * FIN + k] * W0[k * HD + j];
    h[idx] = fmaxf(acc, 0.f);
}

// ---------------- GEMM: A[N,128] @ W[128,128], 64x64 tile ----------------
__launch_bounds__(256, 2)
static __global__ void k_gemm128(const float* __restrict__ A, const float* __restrict__ W,
                                 float* __restrict__ out) {
    __shared__ float As[64][128];   // 32 KB
    __shared__ float Ws[128][64];   // 32 KB
    int nb = blockIdx.x >> 1;
    int jb = (blockIdx.x & 1) * 64;
    int n0 = nb * 64;
    int t = threadIdx.x;
    for (int i = t; i < 64 * 32; i += 256) {
        int n = i >> 5, k4 = i & 31;
        reinterpret_cast<float4*>(&As[n][0])[k4] =
            reinterpret_cast<const float4*>(A + (size_t)(n0 + n) * HD)[k4];
    }
    for (int i = t; i < 128 * 16; i += 256) {
        int k = i >> 4, j4 = i & 15;
        reinterpret_cast<float4*>(&Ws[k][0])[j4] =
            reinterpret_cast<const float4*>(W + (size_t)k * HD + jb)[j4];
    }
    __syncthreads();
    int tn = (t >> 4) * 4;
    int tj = (t & 15) * 4;
    float acc[4][4] = {};
#pragma unroll 4
    for (int k = 0; k < 128; ++k) {
        float a0 = As[tn + 0][k], a1 = As[tn + 1][k], a2 = As[tn + 2][k], a3 = As[tn + 3][k];
        float4 b = *reinterpret_cast<const float4*>(&Ws[k][tj]);
        acc[0][0] += a0 * b.x; acc[0][1] += a0 * b.y; acc[0][2] += a0 * b.z; acc[0][3] += a0 * b.w;
        acc[1][0] += a1 * b.x; acc[1][1] += a1 * b.y; acc[1][2] += a1 * b.z; acc[1][3] += a1 * b.w;
        acc[2][0] += a2 * b.x; acc[2][1] += a2 * b.y; acc[2][2] += a2 * b.z; acc[2][3] += a2 * b.w;
        acc[3][0] += a3 * b.x; acc[3][1] += a3 * b.y; acc[3][2] += a3 * b.z; acc[3][3] += a3 * b.w;
    }
    for (int i = 0; i < 4; ++i) {
        float4 v = make_float4(acc[i][0], acc[i][1], acc[i][2], acc[i][3]);
        *reinterpret_cast<float4*>(out + (size_t)(n0 + tn + i) * HD + jb + tj) = v;
    }
}

// ---------------- CSR gather + self-loop + bias + relu (fused) ----------------
__launch_bounds__(256)
static __global__ void k_gather128(const float* __restrict__ t, const float* __restrict__ dinv,
                                   const int* __restrict__ row_ptr, const int* __restrict__ csr_src,
                                   const float* __restrict__ csr_w, const float* __restrict__ b,
                                   float* __restrict__ out) {
    int n = blockIdx.x * 4 + (threadIdx.x >> 6);
    if (n >= NN) return;
    int f = (threadIdx.x & 63) * 2;
    int s = row_ptr[n], e = row_ptr[n + 1];
    float accx = 0.f, accy = 0.f;
    for (int i = s; i < e; ++i) {
        int src = csr_src[i];
        float w = csr_w[i];
        float2 v = *reinterpret_cast<const float2*>(t + (size_t)src * HD + f);
        accx += w * v.x;
        accy += w * v.y;
    }
    float d = dinv[n], d2 = d * d;
    float2 sv = *reinterpret_cast<const float2*>(t + (size_t)n * HD + f);
    accx = fmaxf(accx + d2 * sv.x + b[f], 0.f);
    accy = fmaxf(accy + d2 * sv.y + b[f + 1], 0.f);
    *reinterpret_cast<float2*>(out + (size_t)n * HD + f) = make_float2(accx, accy);
}

// ---------------- pooling ----------------
static __global__ void k_ranges(const int* __restrict__ batch, int* __restrict__ start) {
    int g = blockIdx.x * 256 + threadIdx.x;
    if (g > NG) return;
    int lo = 0, hi = NN;
    while (lo < hi) {
        int mid = (lo + hi) >> 1;
        if (batch[mid] < g) lo = mid + 1; else hi = mid;
    }
    start[g] = lo;
}

static __global__ void k_pool(const float* __restrict__ h, const int* __restrict__ start,
                              float* __restrict__ gx) {
    int g = blockIdx.x;
    int j = threadIdx.x;   // 128
    int s = start[g], e = start[g + 1];
    float acc = 0.f;
    for (int n = s; n < e; ++n) acc += h[(size_t)n * HD + j];
    float cnt = (float)(e - s);
    gx[(size_t)g * HD + j] = acc / fmaxf(cnt, 1.0f);
}

// ---------------- FFN ----------------
static __global__ void k_ffn1(const float* __restrict__ gx, const float* __restrict__ Wf1,
                              const float* __restrict__ bf1, float* __restrict__ z) {
    int idx = blockIdx.x * 256 + threadIdx.x;
    if (idx >= NG * HD) return;
    int g = idx >> 7, j = idx & 127;
    float acc = bf1[j];
#pragma unroll 8
    for (int k = 0; k < HD; ++k) acc += gx[(size_t)g * HD + k] * Wf1[k * HD + j];
    z[idx] = fmaxf(acc, 0.f);
}

static __global__ void k_ffn2(const float* __restrict__ z, const float* __restrict__ Wf2,
                              const float* __restrict__ bf2, float* __restrict__ out) {
    int idx = blockIdx.x * 256 + threadIdx.x;
    if (idx >= NG * CO) return;
    int g = idx >> 1, c = idx & 1;
    float acc = bf2[c];
#pragma unroll 8
    for (int k = 0; k < HD; ++k) acc += z[(size_t)g * HD + k] * Wf2[k * CO + c];
    out[idx] = acc;
}

extern "C" void kernel_launch(void* const* d_in, const int* in_sizes, int n_in,
                              void* d_out, int out_size, void* d_ws, size_t ws_size,
                              hipStream_t stream) {
    const float* x     = (const float*)d_in[0];
    const int*   ei    = (const int*)d_in[1];
    const float* ew    = (const float*)d_in[2];
    const int*   batch = (const int*)d_in[3];
    const float* W0  = (const float*)d_in[4];
    const float* b0  = (const float*)d_in[5];
    const float* W1  = (const float*)d_in[6];
    const float* b1  = (const float*)d_in[7];
    const float* W2  = (const float*)d_in[8];
    const float* b2  = (const float*)d_in[9];
    const float* Wf1 = (const float*)d_in[10];
    const float* bf1 = (const float*)d_in[11];
    const float* Wf2 = (const float*)d_in[12];
    const float* bf2 = (const float*)d_in[13];
    float* out = (float*)d_out;

    char* ws = (char*)d_ws;
    float* bufA   = (float*)ws;  ws += (size_t)NN * HD * 4;     // 102.4 MB
    float* bufB   = (float*)ws;  ws += (size_t)NN * HD * 4;     // 102.4 MB
    float* dinv   = (float*)ws;  ws += (size_t)NN * 4;          // 800 KB
    int*   cnt    = (int*)ws;    ws += (size_t)NN * 4;          // 800 KB (reused as cursor)
    int*   row_ptr= (int*)ws;    ws += (size_t)(NN + 1) * 4;    // 800 KB
    int*   bsum   = (int*)ws;    ws += 1024;                    // block sums
    int*   csr_src= (int*)ws;    ws += (size_t)NE * 4;          // 2.4 MB
    float* csr_w  = (float*)ws;  ws += (size_t)NE * 4;          // 2.4 MB
    if ((size_t)(ws - (char*)d_ws) > ws_size) return;
    // dead-buffer aliases for the tail stage (bufA unused after last gather)
    float* xs  = bufA;                   // [N,9] propagated raw features
    float* gx  = bufA;                   // [G,128] pooled
    float* z   = bufA + (size_t)NG * HD; // [G,128] ffn hidden
    int* start = (int*)(bufA + (size_t)2 * NG * HD);

    const int nb  = (NN + 255) / 256;      // 782
    const int ebk = (NE + 255) / 256;      // 2344

    // degree + edge counts
    hipMemsetAsync(cnt, 0, (size_t)NN * 4, stream);
    k_init_deg<<<nb, 256, 0, stream>>>(dinv);
    k_deg_cnt<<<ebk, 256, 0, stream>>>(ei, ew, dinv, cnt);
    k_dinv<<<nb, 256, 0, stream>>>(dinv);

    // CSR build
    k_scan1<<<NBLK_SCAN, 256, 0, stream>>>(cnt, row_ptr, bsum);
    k_scan2<<<1, 256, 0, stream>>>(bsum);
    k_scan3<<<nb, 256, 0, stream>>>(bsum, row_ptr);
    hipMemsetAsync(cnt, 0, (size_t)NN * 4, stream);   // cursor
    k_fill<<<ebk, 256, 0, stream>>>(ei, ew, dinv, row_ptr, cnt, csr_src, csr_w);

    // ---- layer 0: propagate 9-dim, then fused GEMM+bias+relu ----
    k_prop9<<<nb, 256, 0, stream>>>(x, dinv, row_ptr, csr_src, csr_w, xs);
    k_gemm0f<<<(NN * HD + 255) / 256, 256, 0, stream>>>(xs, W0, b0, bufB);

    // ---- layer 1 ----
    k_gemm128<<<(NN / 64) * 2, 256, 0, stream>>>(bufB, W1, bufA);
    k_gather128<<<(NN + 3) / 4, 256, 0, stream>>>(bufA, dinv, row_ptr, csr_src, csr_w, b1, bufB);

    // ---- layer 2 ----
    k_gemm128<<<(NN / 64) * 2, 256, 0, stream>>>(bufB, W2, bufA);
    k_gather128<<<(NN + 3) / 4, 256, 0, stream>>>(bufA, dinv, row_ptr, csr_src, csr_w, b2, bufB);

    // ---- pooling + FFN ----
    k_ranges<<<(NG + 1 + 255) / 256, 256, 0, stream>>>(batch, start);
    k_pool<<<NG, 128, 0, stream>>>(bufB, start, gx);
    k_ffn1<<<(NG * HD + 255) / 256, 256, 0, stream>>>(gx, Wf1, bf1, z);
    k_ffn2<<<(NG * CO + 255) / 256, 256, 0, stream>>>(z, Wf2, bf2, out);
}

// Round 17
// 719.963 us; speedup vs baseline: 3.0170x; 1.0517x over previous
//
#include <hip/hip_runtime.h>

#define NN 200000   // nodes
#define NE 600000   // edges
#define NG 8192     // graphs
#define FIN 9
#define HD 128
#define CO 2
#define NBLK_SCAN ((NN + 1023) / 1024)   // 196

// ---------------- degree + edge-count ----------------
static __global__ void k_init_deg(float* deg) {
    int i = blockIdx.x * 256 + threadIdx.x;
    if (i < NN) deg[i] = 1.0f;              // self-loop weight
}

static __global__ void k_deg_cnt(const int* __restrict__ ei, const float* __restrict__ ew,
                                 float* deg, int* cnt) {
    int e = blockIdx.x * 256 + threadIdx.x;
    if (e < NE) {
        int dst = ei[NE + e];
        atomicAdd(&deg[dst], ew[e]);
        atomicAdd(&cnt[dst], 1);
    }
}

static __global__ void k_dinv(float* deg) {
    int i = blockIdx.x * 256 + threadIdx.x;
    if (i < NN) {
        float d = deg[i];
        deg[i] = d > 0.0f ? rsqrtf(d) : 0.0f;
    }
}

// ---------------- prefix scan (counts -> row_ptr) ----------------
static __global__ void k_scan1(const int* __restrict__ cnt, int* __restrict__ row_ptr,
                               int* __restrict__ bsum) {
    __shared__ int lds[256];
    int b = blockIdx.x, t = threadIdx.x;
    int base = b * 1024 + t * 4;
    int c[4];
    int s = 0;
#pragma unroll
    for (int u = 0; u < 4; ++u) {
        int i = base + u;
        c[u] = (i < NN) ? cnt[i] : 0;
        s += c[u];
    }
    lds[t] = s;
    __syncthreads();
    for (int off = 1; off < 256; off <<= 1) {
        int v = (t >= off) ? lds[t - off] : 0;
        __syncthreads();
        lds[t] += v;
        __syncthreads();
    }
    int run = lds[t] - s;   // exclusive offset within block
#pragma unroll
    for (int u = 0; u < 4; ++u) {
        run += c[u];
        int i = base + u;
        if (i < NN) row_ptr[1 + i] = run;
    }
    if (t == 255) bsum[b] = lds[255];
}

static __global__ void k_scan2(int* bsum) {
    __shared__ int lds[256];
    int t = threadIdx.x;
    lds[t] = (t < NBLK_SCAN) ? bsum[t] : 0;
    __syncthreads();
    for (int off = 1; off < 256; off <<= 1) {
        int v = (t >= off) ? lds[t - off] : 0;
        __syncthreads();
        lds[t] += v;
        __syncthreads();
    }
    if (t < NBLK_SCAN) bsum[t] = lds[t];
}

static __global__ void k_scan3(const int* __restrict__ bsum, int* __restrict__ row_ptr) {
    int i = blockIdx.x * 256 + threadIdx.x;
    if (i == 0) row_ptr[0] = 0;
    if (i < NN) {
        int b = i >> 10;
        int off = b ? bsum[b - 1] : 0;
        row_ptr[1 + i] += off;
    }
}

// fill CSR: per-edge slot grab (cursor = reused cnt buffer, re-zeroed)
static __global__ void k_fill(const int* __restrict__ ei, const float* __restrict__ ew,
                              const float* __restrict__ dinv, const int* __restrict__ row_ptr,
                              int* cursor, int* __restrict__ csr_src, float* __restrict__ csr_w) {
    int e = blockIdx.x * 256 + threadIdx.x;
    if (e >= NE) return;
    int src = ei[e], dst = ei[NE + e];
    int pos = row_ptr[dst] + atomicAdd(&cursor[dst], 1);
    csr_src[pos] = src;
    csr_w[pos] = dinv[src] * ew[e] * dinv[dst];
}

// ---------------- layer 0: propagate raw 9-dim x, then fused GEMM ----------------
static __global__ void k_prop9(const float* __restrict__ x, const float* __restrict__ dinv,
                               const int* __restrict__ row_ptr, const int* __restrict__ csr_src,
                               const float* __restrict__ csr_w, float* __restrict__ xs) {
    int n = blockIdx.x * 256 + threadIdx.x;
    if (n >= NN) return;
    float acc[FIN] = {};
    int s = row_ptr[n], e = row_ptr[n + 1];
    for (int i = s; i < e; ++i) {
        int src = csr_src[i];
        float w = csr_w[i];
#pragma unroll
        for (int k = 0; k < FIN; ++k) acc[k] += w * x[src * FIN + k];
    }
    float d = dinv[n], d2 = d * d;
#pragma unroll
    for (int k = 0; k < FIN; ++k) xs[n * FIN + k] = acc[k] + d2 * x[n * FIN + k];
}

static __global__ void k_gemm0f(const float* __restrict__ xs, const float* __restrict__ W0,
                                const float* __restrict__ b0, float* __restrict__ h) {
    int idx = blockIdx.x * 256 + threadIdx.x;
    if (idx >= NN * HD) return;
    int n = idx >> 7, j = idx & 127;
    float acc = b0[j];
#pragma unroll
    for (int k = 0; k < FIN; ++k) acc += xs[n * FIN + k] * W0[k * HD + j];
    h[idx] = fmaxf(acc, 0.f);
}

// ---------------- GEMM: A[N,128] @ W[128,128], 64x64 tile ----------------
// As stride padded 128 -> 132: tn-group spacing 528 floats == 16 (mod 32) ->
// 2-way bank aliasing (free, m136) instead of 16-way (5.7x, 1.28e7 conflicts measured).
// 132 keeps rows 16B-aligned (528 B) for the float4 staging writes.
__launch_bounds__(256, 2)
static __global__ void k_gemm128(const float* __restrict__ A, const float* __restrict__ W,
                                 float* __restrict__ out) {
    __shared__ float As[64][132];   // 33 KB (padded)
    __shared__ float Ws[128][64];   // 32 KB
    int nb = blockIdx.x >> 1;
    int jb = (blockIdx.x & 1) * 64;
    int n0 = nb * 64;
    int t = threadIdx.x;
    for (int i = t; i < 64 * 32; i += 256) {
        int n = i >> 5, k4 = i & 31;
        reinterpret_cast<float4*>(&As[n][0])[k4] =
            reinterpret_cast<const float4*>(A + (size_t)(n0 + n) * HD)[k4];
    }
    for (int i = t; i < 128 * 16; i += 256) {
        int k = i >> 4, j4 = i & 15;
        reinterpret_cast<float4*>(&Ws[k][0])[j4] =
            reinterpret_cast<const float4*>(W + (size_t)k * HD + jb)[j4];
    }
    __syncthreads();
    int tn = (t >> 4) * 4;
    int tj = (t & 15) * 4;
    float acc[4][4] = {};
#pragma unroll 4
    for (int k = 0; k < 128; ++k) {
        float a0 = As[tn + 0][k], a1 = As[tn + 1][k], a2 = As[tn + 2][k], a3 = As[tn + 3][k];
        float4 b = *reinterpret_cast<const float4*>(&Ws[k][tj]);
        acc[0][0] += a0 * b.x; acc[0][1] += a0 * b.y; acc[0][2] += a0 * b.z; acc[0][3] += a0 * b.w;
        acc[1][0] += a1 * b.x; acc[1][1] += a1 * b.y; acc[1][2] += a1 * b.z; acc[1][3] += a1 * b.w;
        acc[2][0] += a2 * b.x; acc[2][1] += a2 * b.y; acc[2][2] += a2 * b.z; acc[2][3] += a2 * b.w;
        acc[3][0] += a3 * b.x; acc[3][1] += a3 * b.y; acc[3][2] += a3 * b.z; acc[3][3] += a3 * b.w;
    }
    for (int i = 0; i < 4; ++i) {
        float4 v = make_float4(acc[i][0], acc[i][1], acc[i][2], acc[i][3]);
        *reinterpret_cast<float4*>(out + (size_t)(n0 + tn + i) * HD + jb + tj) = v;
    }
}

// ---------------- CSR gather + self-loop + bias + relu (fused) ----------------
__launch_bounds__(256)
static __global__ void k_gather128(const float* __restrict__ t, const float* __restrict__ dinv,
                                   const int* __restrict__ row_ptr, const int* __restrict__ csr_src,
                                   const float* __restrict__ csr_w, const float* __restrict__ b,
                                   float* __restrict__ out) {
    int n = blockIdx.x * 4 + (threadIdx.x >> 6);
    if (n >= NN) return;
    int f = (threadIdx.x & 63) * 2;
    int s = row_ptr[n], e = row_ptr[n + 1];
    float accx = 0.f, accy = 0.f;
    for (int i = s; i < e; ++i) {
        int src = csr_src[i];
        float w = csr_w[i];
        float2 v = *reinterpret_cast<const float2*>(t + (size_t)src * HD + f);
        accx += w * v.x;
        accy += w * v.y;
    }
    float d = dinv[n], d2 = d * d;
    float2 sv = *reinterpret_cast<const float2*>(t + (size_t)n * HD + f);
    accx = fmaxf(accx + d2 * sv.x + b[f], 0.f);
    accy = fmaxf(accy + d2 * sv.y + b[f + 1], 0.f);
    *reinterpret_cast<float2*>(out + (size_t)n * HD + f) = make_float2(accx, accy);
}

// ---------------- pooling ----------------
static __global__ void k_ranges(const int* __restrict__ batch, int* __restrict__ start) {
    int g = blockIdx.x * 256 + threadIdx.x;
    if (g > NG) return;
    int lo = 0, hi = NN;
    while (lo < hi) {
        int mid = (lo + hi) >> 1;
        if (batch[mid] < g) lo = mid + 1; else hi = mid;
    }
    start[g] = lo;
}

static __global__ void k_pool(const float* __restrict__ h, const int* __restrict__ start,
                              float* __restrict__ gx) {
    int g = blockIdx.x;
    int j = threadIdx.x;   // 128
    int s = start[g], e = start[g + 1];
    float acc = 0.f;
    for (int n = s; n < e; ++n) acc += h[(size_t)n * HD + j];
    float cnt = (float)(e - s);
    gx[(size_t)g * HD + j] = acc / fmaxf(cnt, 1.0f);
}

// ---------------- FFN ----------------
static __global__ void k_ffn1(const float* __restrict__ gx, const float* __restrict__ Wf1,
                              const float* __restrict__ bf1, float* __restrict__ z) {
    int idx = blockIdx.x * 256 + threadIdx.x;
    if (idx >= NG * HD) return;
    int g = idx >> 7, j = idx & 127;
    float acc = bf1[j];
#pragma unroll 8
    for (int k = 0; k < HD; ++k) acc += gx[(size_t)g * HD + k] * Wf1[k * HD + j];
    z[idx] = fmaxf(acc, 0.f);
}

static __global__ void k_ffn2(const float* __restrict__ z, const float* __restrict__ Wf2,
                              const float* __restrict__ bf2, float* __restrict__ out) {
    int idx = blockIdx.x * 256 + threadIdx.x;
    if (idx >= NG * CO) return;
    int g = idx >> 1, c = idx & 1;
    float acc = bf2[c];
#pragma unroll 8
    for (int k = 0; k < HD; ++k) acc += z[(size_t)g * HD + k] * Wf2[k * CO + c];
    out[idx] = acc;
}

extern "C" void kernel_launch(void* const* d_in, const int* in_sizes, int n_in,
                              void* d_out, int out_size, void* d_ws, size_t ws_size,
                              hipStream_t stream) {
    const float* x     = (const float*)d_in[0];
    const int*   ei    = (const int*)d_in[1];
    const float* ew    = (const float*)d_in[2];
    const int*   batch = (const int*)d_in[3];
    const float* W0  = (const float*)d_in[4];
    const float* b0  = (const float*)d_in[5];
    const float* W1  = (const float*)d_in[6];
    const float* b1  = (const float*)d_in[7];
    const float* W2  = (const float*)d_in[8];
    const float* b2  = (const float*)d_in[9];
    const float* Wf1 = (const float*)d_in[10];
    const float* bf1 = (const float*)d_in[11];
    const float* Wf2 = (const float*)d_in[12];
    const float* bf2 = (const float*)d_in[13];
    float* out = (float*)d_out;

    char* ws = (char*)d_ws;
    float* bufA   = (float*)ws;  ws += (size_t)NN * HD * 4;     // 102.4 MB
    float* bufB   = (float*)ws;  ws += (size_t)NN * HD * 4;     // 102.4 MB
    float* dinv   = (float*)ws;  ws += (size_t)NN * 4;          // 800 KB
    int*   cnt    = (int*)ws;    ws += (size_t)NN * 4;          // 800 KB (reused as cursor)
    int*   row_ptr= (int*)ws;    ws += (size_t)(NN + 1) * 4;    // 800 KB
    int*   bsum   = (int*)ws;    ws += 1024;                    // block sums
    int*   csr_src= (int*)ws;    ws += (size_t)NE * 4;          // 2.4 MB
    float* csr_w  = (float*)ws;  ws += (size_t)NE * 4;          // 2.4 MB
    if ((size_t)(ws - (char*)d_ws) > ws_size) return;
    // dead-buffer aliases for the tail stage (bufA unused after last gather)
    float* xs  = bufA;                   // [N,9] propagated raw features
    float* gx  = bufA;                   // [G,128] pooled
    float* z   = bufA + (size_t)NG * HD; // [G,128] ffn hidden
    int* start = (int*)(bufA + (size_t)2 * NG * HD);

    const int nb  = (NN + 255) / 256;      // 782
    const int ebk = (NE + 255) / 256;      // 2344

    // degree + edge counts
    hipMemsetAsync(cnt, 0, (size_t)NN * 4, stream);
    k_init_deg<<<nb, 256, 0, stream>>>(dinv);
    k_deg_cnt<<<ebk, 256, 0, stream>>>(ei, ew, dinv, cnt);
    k_dinv<<<nb, 256, 0, stream>>>(dinv);

    // CSR build
    k_scan1<<<NBLK_SCAN, 256, 0, stream>>>(cnt, row_ptr, bsum);
    k_scan2<<<1, 256, 0, stream>>>(bsum);
    k_scan3<<<nb, 256, 0, stream>>>(bsum, row_ptr);
    hipMemsetAsync(cnt, 0, (size_t)NN * 4, stream);   // cursor
    k_fill<<<ebk, 256, 0, stream>>>(ei, ew, dinv, row_ptr, cnt, csr_src, csr_w);

    // ---- layer 0: propagate 9-dim, then fused GEMM+bias+relu ----
    k_prop9<<<nb, 256, 0, stream>>>(x, dinv, row_ptr, csr_src, csr_w, xs);
    k_gemm0f<<<(NN * HD + 255) / 256, 256, 0, stream>>>(xs, W0, b0, bufB);

    // ---- layer 1 ----
    k_gemm128<<<(NN / 64) * 2, 256, 0, stream>>>(bufB, W1, bufA);
    k_gather128<<<(NN + 3) / 4, 256, 0, stream>>>(bufA, dinv, row_ptr, csr_src, csr_w, b1, bufB);

    // ---- layer 2 ----
    k_gemm128<<<(NN / 64) * 2, 256, 0, stream>>>(bufB, W2, bufA);
    k_gather128<<<(NN + 3) / 4, 256, 0, stream>>>(bufA, dinv, row_ptr, csr_src, csr_w, b2, bufB);

    // ---- pooling + FFN ----
    k_ranges<<<(NG + 1 + 255) / 256, 256, 0, stream>>>(batch, start);
    k_pool<<<NG, 128, 0, stream>>>(bufB, start, gx);
    k_ffn1<<<(NG * HD + 255) / 256, 256, 0, stream>>>(gx, Wf1, bf1, z);
    k_ffn2<<<(NG * CO + 255) / 256, 256, 0, stream>>>(z, Wf2, bf2, out);
}